// Round 2
// baseline (448.715 us; speedup 1.0000x reference)
//
#include <hip/hip_runtime.h>
#include <stdint.h>

#define NN 50000
#define EE 800000
#define DD 128
#define RR 4
#define LL 3
#define NRSEG (NN*RR)                    // 200000 segments (dst*4 + etype)
#define NKB 20                           // K=640 in chunks of 32
#define NB_SCAN ((NRSEG + 1023)/1024)    // 196 scan blocks

typedef _Float16 f16;
typedef _Float16 f16x8 __attribute__((ext_vector_type(8)));
typedef float f32x4 __attribute__((ext_vector_type(4)));

union U32H { uint32_t u; f16 h[2]; };

// ---------------- CSR build ----------------
__global__ __launch_bounds__(256) void k_hist(const int* __restrict__ ei, const int* __restrict__ et,
                                              int* __restrict__ cnt){
  int e = blockIdx.x*256 + threadIdx.x;
  if(e < EE) atomicAdd(&cnt[ei[EE+e]*RR + et[e]], 1);
}

__global__ __launch_bounds__(256) void k_reduce(const int* __restrict__ cnt, int* __restrict__ bsum){
  __shared__ int s[256];
  int b = blockIdx.x, t = threadIdx.x;
  int base = b*1024 + t*4;
  int v = 0;
  #pragma unroll
  for(int j=0;j<4;j++){ int i = base+j; if(i<NRSEG) v += cnt[i]; }
  s[t]=v; __syncthreads();
  for(int o=128;o>0;o>>=1){ if(t<o) s[t]+=s[t+o]; __syncthreads(); }
  if(t==0) bsum[b]=s[0];
}

__global__ __launch_bounds__(256) void k_top(const int* __restrict__ bsum, int* __restrict__ boff,
                                             int* __restrict__ rowp, int nb){
  __shared__ int s[256];
  int t=threadIdx.x;
  int v = (t<nb)? bsum[t] : 0;
  s[t]=v; __syncthreads();
  for(int o=1;o<256;o<<=1){ int x=(t>=o)?s[t-o]:0; __syncthreads(); s[t]+=x; __syncthreads(); }
  if(t<nb) boff[t] = s[t]-v;
  if(t==255) rowp[NRSEG] = s[255];
}

__global__ __launch_bounds__(256) void k_scan(const int* __restrict__ cnt, const int* __restrict__ boff,
                                              int* __restrict__ rowp){
  __shared__ int s[256];
  int b=blockIdx.x, t=threadIdx.x;
  int base = b*1024 + t*4;
  int c[4]; int tot=0;
  #pragma unroll
  for(int j=0;j<4;j++){ int i=base+j; c[j] = (i<NRSEG)? cnt[i]:0; tot+=c[j]; }
  s[t]=tot; __syncthreads();
  for(int o=1;o<256;o<<=1){ int x=(t>=o)?s[t-o]:0; __syncthreads(); s[t]+=x; __syncthreads(); }
  int run = boff[b] + s[t]-tot;
  #pragma unroll
  for(int j=0;j<4;j++){
    int i=base+j;
    if(i<NRSEG){ rowp[i]=run; run+=c[j]; }
  }
}

__global__ __launch_bounds__(256) void k_scatter(const int* __restrict__ ei, const int* __restrict__ et,
                                                 int* __restrict__ cursor, int* __restrict__ ssrc){
  int e = blockIdx.x*256 + threadIdx.x;
  if(e < EE){
    int seg = ei[EE+e]*RR + et[e];
    int p = atomicAdd(&cursor[seg], 1);
    ssrc[p] = ei[e];
  }
}

// ---------------- dtype converts ----------------
// Wf fragment-order: t = ((l*NKB+kb)*8+cb)*64+lane, 8 halves each:
//   Wf[t*8+e] = Wcat[k = kb*32 + (lane>>4)*8 + e][col = cb*16 + (lane&15)]
__global__ __launch_bounds__(256) void k_wconv(const float* __restrict__ W, const float* __restrict__ root,
                                               f16* __restrict__ Wf){
  int t = blockIdx.x*256 + threadIdx.x;
  if(t >= LL*NKB*8*64) return;
  int lane = t & 63;
  int cb   = (t>>6) & 7;
  int kb   = (t>>9) % NKB;
  int l    = (t>>9) / NKB;
  int col  = cb*16 + (lane&15);
  int kbase= kb*32 + (lane>>4)*8;
  f16* dst = Wf + (size_t)t*8;
  #pragma unroll
  for(int e=0;e<8;e++){
    int k = kbase+e;
    float v = (k < 4*DD) ? W[(((size_t)l*RR + (k>>7))*DD + (k&127))*DD + col]
                         : root[((size_t)l*DD + (k-4*DD))*DD + col];
    dst[e] = (f16)v;
  }
}

__global__ __launch_bounds__(256) void k_xconv(const float* __restrict__ x, f16* __restrict__ x16){
  int t = blockIdx.x*256 + threadIdx.x;
  if(t < NN*DD) x16[t] = (f16)x[t];
}

// ---------------- aggregation: one wave per dst node, 4 relations in-register ----------------
__device__ __forceinline__ void accum4(float acc[4][4], uint2 v, int j, bool act,
                                       int t1, int t2, int t3){
  U32H u0, u1; u0.u = v.x; u1.u = v.y;
  float f0 = (float)u0.h[0], f1 = (float)u0.h[1];
  float f2 = (float)u1.h[0], f3 = (float)u1.h[1];
  int rr = (j>=t1) + (j>=t2) + (j>=t3);
  #pragma unroll
  for(int r=0;r<4;r++){
    bool m = act && (rr==r);
    acc[r][0] += m ? f0 : 0.f;
    acc[r][1] += m ? f1 : 0.f;
    acc[r][2] += m ? f2 : 0.f;
    acc[r][3] += m ? f3 : 0.f;
  }
}

__global__ __launch_bounds__(256) void k_agg(const f16* __restrict__ x16, const int* __restrict__ rowp,
                                             const int* __restrict__ ssrc, f16* __restrict__ A16){
  int node = (blockIdx.x*256 + threadIdx.x) >> 6;
  if(node >= NN) return;
  int lane = threadIdx.x & 63;
  int half = lane >> 5, col2 = lane & 31;
  const uint2* xu = (const uint2*)x16;

  int np = node*RR;
  int rv = (lane < 5) ? rowp[np + lane] : 0;
  int b0 = __shfl(rv, 0);
  int t1 = __shfl(rv, 1) - b0;
  int t2 = __shfl(rv, 2) - b0;
  int t3 = __shfl(rv, 3) - b0;
  int n  = __shfl(rv, 4) - b0;

  float acc[4][4];
  #pragma unroll
  for(int r=0;r<4;r++)
    #pragma unroll
    for(int k=0;k<4;k++) acc[r][k] = 0.f;

  for(int base=0; base<n; base+=64){
    int nn = min(n-base, 64);
    int sv = (lane < nn) ? ssrc[b0+base+lane] : 0;
    for(int jj=0; jj<nn; jj+=4){
      int i0 = jj + half, i1 = jj + 2 + half;
      int s0 = __shfl(sv, i0);
      int s1 = __shfl(sv, i1);
      uint2 v0 = xu[(size_t)s0*32 + col2];
      uint2 v1 = xu[(size_t)s1*32 + col2];
      accum4(acc, v0, base+i0, i0<nn, t1, t2, t3);
      accum4(acc, v1, base+i1, i1<nn, t1, t2, t3);
    }
  }

  // combine half-waves (edges were split lo/hi)
  #pragma unroll
  for(int r=0;r<4;r++)
    #pragma unroll
    for(int k=0;k<4;k++) acc[r][k] += __shfl_xor(acc[r][k], 32);

  float iv0 = 1.f/(float)max(t1,1);
  float iv1 = 1.f/(float)max(t2-t1,1);
  float iv2 = 1.f/(float)max(t3-t2,1);
  float iv3 = 1.f/(float)max(n -t3,1);
  // half 0 stores relations 0,1 ; half 1 stores relations 2,3
  float sA = half ? iv2 : iv0;
  float sB = half ? iv3 : iv1;
  float aA[4], aB[4];
  #pragma unroll
  for(int k=0;k<4;k++){
    aA[k] = (half ? acc[2][k] : acc[0][k]) * sA;
    aB[k] = (half ? acc[3][k] : acc[1][k]) * sB;
  }
  U32H p0,p1,p2,p3;
  p0.h[0]=(f16)aA[0]; p0.h[1]=(f16)aA[1];
  p1.h[0]=(f16)aA[2]; p1.h[1]=(f16)aA[3];
  p2.h[0]=(f16)aB[0]; p2.h[1]=(f16)aB[1];
  p3.h[0]=(f16)aB[2]; p3.h[1]=(f16)aB[3];
  uint2* au = (uint2*)A16;
  int rA = np + half*2;
  uint2 oA; oA.x = p0.u; oA.y = p1.u;
  uint2 oB; oB.x = p2.u; oB.y = p3.u;
  au[(size_t)rA*32 + col2]     = oA;
  au[(size_t)(rA+1)*32 + col2] = oB;
}

// ---------------- GEMM (M=NN, K=640, N=128) + fused epilogue ----------------
// Block = 256 threads (4 waves), BM=128 rows; wave owns 32 rows x 128 cols.
__device__ __forceinline__ void stageB(const f16* __restrict__ Wf, f16* lds, int kb, int wid, int lane){
  const f16* src = Wf + (size_t)kb*4096;
  #pragma unroll
  for(int j=wid;j<8;j+=4){
    __builtin_amdgcn_global_load_lds((const __attribute__((address_space(1))) void*)(src + j*512 + lane*8),
                                     (__attribute__((address_space(3))) void*)(lds + j*512), 16, 0, 0);
  }
}

template<int LAST>
__global__ __launch_bounds__(256) void k_gemm(const f16* __restrict__ A16, const f16* __restrict__ x16,
                                              const f16* __restrict__ Wf,
                                              const float* __restrict__ bias, const float* __restrict__ gmm,
                                              const float* __restrict__ bet,
                                              f16* __restrict__ xnext, float* __restrict__ outf){
  __shared__ f16 Blds[2][4096];   // [buf][cb*512 + lane*8 + e]
  int tid  = threadIdx.x;
  int lane = tid & 63, wid = tid >> 6;
  int rbase = blockIdx.x*128 + wid*32;          // this wave's first row
  int fr = lane & 15, kg = lane >> 4;

  int arow0 = rbase + fr;       if(arow0 >= NN) arow0 = NN-1;
  int arow1 = rbase + 16 + fr;  if(arow1 >= NN) arow1 = NN-1;
  const f16* Ar0 = A16 + (size_t)arow0*512 + kg*8;
  const f16* Ar1 = A16 + (size_t)arow1*512 + kg*8;
  const f16* Xr0 = x16 + (size_t)arow0*128 + kg*8;
  const f16* Xr1 = x16 + (size_t)arow1*128 + kg*8;

  f32x4 acc[2][8];
  #pragma unroll
  for(int r=0;r<2;r++)
    #pragma unroll
    for(int c=0;c<8;c++) acc[r][c] = (f32x4){0.f,0.f,0.f,0.f};

  f16x8 a0, a1;
  a0 = *(const f16x8*)(Ar0); a1 = *(const f16x8*)(Ar1);
  stageB(Wf, &Blds[0][0], 0, wid, lane);

  for(int kb=0; kb<NKB; kb++){
    __syncthreads();                                   // stage(kb) done, prev reads done
    if(kb+1 < NKB) stageB(Wf, &Blds[(kb+1)&1][0], kb+1, wid, lane);
    f16x8 na0 = a0, na1 = a1;
    if(kb+1 < NKB){
      if(kb+1 < 16){ na0 = *(const f16x8*)(Ar0 + (kb+1)*32); na1 = *(const f16x8*)(Ar1 + (kb+1)*32); }
      else         { na0 = *(const f16x8*)(Xr0 + (kb+1-16)*32); na1 = *(const f16x8*)(Xr1 + (kb+1-16)*32); }
    }
    const f16* bb = &Blds[kb&1][lane*8];
    #pragma unroll
    for(int cb=0;cb<8;cb++){
      f16x8 b = *(const f16x8*)(bb + cb*512);
      acc[0][cb] = __builtin_amdgcn_mfma_f32_16x16x32_f16(a0, b, acc[0][cb], 0, 0, 0);
      acc[1][cb] = __builtin_amdgcn_mfma_f32_16x16x32_f16(a1, b, acc[1][cb], 0, 0, 0);
    }
    a0 = na0; a1 = na1;
  }

  // epilogue: bias -> relu -> +residual -> LayerNorm  (C/D: col=lane&15, row=(lane>>4)*4+q)
  float bs[8];
  #pragma unroll
  for(int cb=0;cb<8;cb++) bs[cb] = bias[cb*16 + fr];
  int g4 = kg*4;
  #pragma unroll
  for(int rh=0; rh<2; rh++){
    float vv[8][4];
    #pragma unroll
    for(int cb=0;cb<8;cb++){
      int col = cb*16 + fr;
      #pragma unroll
      for(int q=0;q<4;q++){
        float v = acc[rh][cb][q] + bs[cb];
        v = v > 0.f ? v : 0.f;
        int row = rbase + rh*16 + g4 + q;
        float res = (row < NN) ? (float)x16[(size_t)row*128 + col] : 0.f;
        vv[cb][q] = v + res;
      }
    }
    #pragma unroll
    for(int q=0;q<4;q++){
      float s1=0.f, s2=0.f;
      #pragma unroll
      for(int cb=0;cb<8;cb++){ float v=vv[cb][q]; s1+=v; s2+=v*v; }
      #pragma unroll
      for(int m=1;m<16;m<<=1){ s1 += __shfl_xor(s1,m,16); s2 += __shfl_xor(s2,m,16); }
      float mu  = s1*(1.f/128.f);
      float var = s2*(1.f/128.f) - mu*mu;
      float rs  = rsqrtf(var + 1e-5f);
      int row = rbase + rh*16 + g4 + q;
      if(row < NN){
        #pragma unroll
        for(int cb=0;cb<8;cb++){
          int col = cb*16 + fr;
          float y = (vv[cb][q]-mu)*rs*gmm[col] + bet[col];
          if(LAST) outf[(size_t)row*128 + col] = y;
          else     xnext[(size_t)row*128 + col] = (f16)y;
        }
      }
    }
  }
}

// ---------------- launch ----------------
extern "C" void kernel_launch(void* const* d_in, const int* in_sizes, int n_in,
                              void* d_out, int out_size, void* d_ws, size_t ws_size,
                              hipStream_t stream){
  const float* x    = (const float*)d_in[0];
  const int*   ei   = (const int*)d_in[1];
  const int*   et   = (const int*)d_in[2];
  const float* W    = (const float*)d_in[3];
  const float* root = (const float*)d_in[4];
  const float* bias = (const float*)d_in[5];
  const float* gmm  = (const float*)d_in[6];
  const float* bet  = (const float*)d_in[7];

  char* ws = (char*)d_ws;
  int*   cnt  = (int*)(ws + 0);            // 800000 B (reused as scatter cursor)
  int*   rowp = (int*)(ws + 800768);       // 800004 B
  int*   ssrc = (int*)(ws + 2402304);      // 3.2 MB
  int*   bsum = (int*)(ws + 5602304);      // 1 KB
  int*   boff = (int*)(ws + 5603328);      // 1 KB
  f16*   Wf   = (f16*)(ws + 5604352);      // 491520 B
  f16*   x16a = (f16*)(ws + 6095872);      // 12.8 MB
  f16*   x16b = (f16*)(ws + 18895872);     // 12.8 MB
  f16*   A16  = (f16*)(ws + 31695872);     // 51.2 MB   (total ~82.9 MB)

  hipMemsetAsync(cnt, 0, NRSEG*4, stream);
  k_hist   <<<(EE+255)/256, 256, 0, stream>>>(ei, et, cnt);
  k_reduce <<<NB_SCAN, 256, 0, stream>>>(cnt, bsum);
  k_top    <<<1, 256, 0, stream>>>(bsum, boff, rowp, NB_SCAN);
  k_scan   <<<NB_SCAN, 256, 0, stream>>>(cnt, boff, rowp);
  hipMemcpyAsync(cnt, rowp, NRSEG*4, hipMemcpyDeviceToDevice, stream);
  k_scatter<<<(EE+255)/256, 256, 0, stream>>>(ei, et, cnt, ssrc);
  k_wconv  <<<(LL*NKB*8*64+255)/256, 256, 0, stream>>>(W, root, Wf);
  k_xconv  <<<(NN*DD)/256, 256, 0, stream>>>(x, x16a);

  f16* xc = x16a; f16* xn = x16b;
  for(int l=0; l<LL; l++){
    k_agg<<<(NN+3)/4, 256, 0, stream>>>(xc, rowp, ssrc, A16);
    if(l < LL-1)
      k_gemm<0><<<(NN+127)/128, 256, 0, stream>>>(A16, xc, Wf + (size_t)l*81920,
                                                  bias+l*DD, gmm+l*DD, bet+l*DD, xn, nullptr);
    else
      k_gemm<1><<<(NN+127)/128, 256, 0, stream>>>(A16, xc, Wf + (size_t)l*81920,
                                                  bias+l*DD, gmm+l*DD, bet+l*DD, nullptr, (float*)d_out);
    f16* t = xc; xc = xn; xn = t;
  }
}

// Round 3
// 304.028 us; speedup vs baseline: 1.4759x; 1.4759x over previous
//
#include <hip/hip_runtime.h>
#include <stdint.h>

#define NN 50000
#define EE 800000
#define DD 128
#define RR 4
#define LL 3
#define NRSEG (NN*RR)                    // 200000 segments (dst*4 + etype)
#define NKB 20                           // K=640 in chunks of 32
#define NB_SCAN ((NRSEG + 1023)/1024)    // 196 scan blocks

typedef _Float16 f16;
typedef _Float16 f16x8 __attribute__((ext_vector_type(8)));
typedef float f32x4 __attribute__((ext_vector_type(4)));

union U32H { uint32_t u; f16 h[2]; };
union U4H  { uint4 u; f16 h[8]; };

// ---------------- CSR build ----------------
__global__ __launch_bounds__(256) void k_hist(const int* __restrict__ ei, const int* __restrict__ et,
                                              int* __restrict__ cnt){
  int e = blockIdx.x*256 + threadIdx.x;
  if(e < EE) atomicAdd(&cnt[ei[EE+e]*RR + et[e]], 1);
}

__global__ __launch_bounds__(256) void k_reduce(const int* __restrict__ cnt, int* __restrict__ bsum){
  __shared__ int s[256];
  int b = blockIdx.x, t = threadIdx.x;
  int base = b*1024 + t*4;
  int v = 0;
  #pragma unroll
  for(int j=0;j<4;j++){ int i = base+j; if(i<NRSEG) v += cnt[i]; }
  s[t]=v; __syncthreads();
  for(int o=128;o>0;o>>=1){ if(t<o) s[t]+=s[t+o]; __syncthreads(); }
  if(t==0) bsum[b]=s[0];
}

__global__ __launch_bounds__(256) void k_top(const int* __restrict__ bsum, int* __restrict__ boff,
                                             int* __restrict__ rowp, int nb){
  __shared__ int s[256];
  int t=threadIdx.x;
  int v = (t<nb)? bsum[t] : 0;
  s[t]=v; __syncthreads();
  for(int o=1;o<256;o<<=1){ int x=(t>=o)?s[t-o]:0; __syncthreads(); s[t]+=x; __syncthreads(); }
  if(t<nb) boff[t] = s[t]-v;
  if(t==255) rowp[NRSEG] = s[255];
}

__global__ __launch_bounds__(256) void k_scan(const int* __restrict__ cnt, const int* __restrict__ boff,
                                              int* __restrict__ rowp){
  __shared__ int s[256];
  int b=blockIdx.x, t=threadIdx.x;
  int base = b*1024 + t*4;
  int c[4]; int tot=0;
  #pragma unroll
  for(int j=0;j<4;j++){ int i=base+j; c[j] = (i<NRSEG)? cnt[i]:0; tot+=c[j]; }
  s[t]=tot; __syncthreads();
  for(int o=1;o<256;o<<=1){ int x=(t>=o)?s[t-o]:0; __syncthreads(); s[t]+=x; __syncthreads(); }
  int run = boff[b] + s[t]-tot;
  #pragma unroll
  for(int j=0;j<4;j++){
    int i=base+j;
    if(i<NRSEG){ rowp[i]=run; run+=c[j]; }
  }
}

__global__ __launch_bounds__(256) void k_scatter(const int* __restrict__ ei, const int* __restrict__ et,
                                                 int* __restrict__ cursor, int* __restrict__ ssrc){
  int e = blockIdx.x*256 + threadIdx.x;
  if(e < EE){
    int seg = ei[EE+e]*RR + et[e];
    int p = atomicAdd(&cursor[seg], 1);
    ssrc[p] = ei[e];
  }
}

// ---------------- dtype converts ----------------
// Wf fragment-order: t = ((l*NKB+kb)*8+cb)*64+lane, 8 halves each:
//   Wf[t*8+e] = Wcat[k = kb*32 + (lane>>4)*8 + e][col = cb*16 + (lane&15)]
__global__ __launch_bounds__(256) void k_wconv(const float* __restrict__ W, const float* __restrict__ root,
                                               f16* __restrict__ Wf){
  int t = blockIdx.x*256 + threadIdx.x;
  if(t >= LL*NKB*8*64) return;
  int lane = t & 63;
  int cb   = (t>>6) & 7;
  int kb   = (t>>9) % NKB;
  int l    = (t>>9) / NKB;
  int col  = cb*16 + (lane&15);
  int kbase= kb*32 + (lane>>4)*8;
  f16* dst = Wf + (size_t)t*8;
  #pragma unroll
  for(int e=0;e<8;e++){
    int k = kbase+e;
    float v = (k < 4*DD) ? W[(((size_t)l*RR + (k>>7))*DD + (k&127))*DD + col]
                         : root[((size_t)l*DD + (k-4*DD))*DD + col];
    dst[e] = (f16)v;
  }
}

__global__ __launch_bounds__(256) void k_xconv(const float* __restrict__ x, f16* __restrict__ x16){
  int t = blockIdx.x*256 + threadIdx.x;
  if(t < NN*DD) x16[t] = (f16)x[t];
}

// ---------------- aggregation: one 16-lane quarter-wave per (node,relation) segment ----------------
__device__ __forceinline__ void acc8(float a[8], uint4 v){
  U4H w; w.u = v;
  #pragma unroll
  for(int k=0;k<8;k++) a[k] += (float)w.h[k];
}

__global__ __launch_bounds__(256) void k_agg(const f16* __restrict__ x16, const int* __restrict__ rowp,
                                             const int* __restrict__ ssrc, f16* __restrict__ A16){
  int seg = blockIdx.x*16 + (threadIdx.x >> 4);      // one segment per 16-lane group
  int l   = threadIdx.x & 15;
  if(seg >= NRSEG) return;

  int b = rowp[seg], e = rowp[seg+1];
  int n = e - b;
  const uint4* xl = (const uint4*)x16 + l;           // lane's 16B slice of each row

  float acc[8];
  #pragma unroll
  for(int k=0;k<8;k++) acc[k] = 0.f;

  if(n > 0){
    int c0 = ssrc[b];
    int c1 = (n > 1) ? ssrc[b+1] : c0;
    for(int j=0; j<n; j+=2){
      uint4 v0 = xl[(size_t)c0*16];
      uint4 v1 = xl[(size_t)c1*16];
      if(j+2 < n){
        c0 = ssrc[b+j+2];
        c1 = (j+3 < n) ? ssrc[b+j+3] : c0;
      }
      acc8(acc, v0);
      if(j+1 < n) acc8(acc, v1);
    }
  }

  float inv = 1.f/(float)max(n,1);
  U4H o;
  #pragma unroll
  for(int k=0;k<8;k++) o.h[k] = (f16)(acc[k]*inv);
  ((uint4*)A16)[(size_t)seg*16 + l] = o.u;
}

// ---------------- GEMM (M=NN, K=640, N=128) + fused epilogue ----------------
// Block = 256 threads (4 waves), BM=128 rows; wave owns 32 rows x 128 cols.
__device__ __forceinline__ void stageB(const f16* __restrict__ Wf, f16* lds, int kb, int wid, int lane){
  const f16* src = Wf + (size_t)kb*4096;
  #pragma unroll
  for(int j=wid;j<8;j+=4){
    __builtin_amdgcn_global_load_lds((const __attribute__((address_space(1))) void*)(src + j*512 + lane*8),
                                     (__attribute__((address_space(3))) void*)(lds + j*512), 16, 0, 0);
  }
}

template<int LAST>
__global__ __launch_bounds__(256) void k_gemm(const f16* __restrict__ A16, const f16* __restrict__ x16,
                                              const f16* __restrict__ Wf,
                                              const float* __restrict__ bias, const float* __restrict__ gmm,
                                              const float* __restrict__ bet,
                                              f16* __restrict__ xnext, float* __restrict__ outf){
  __shared__ f16 Blds[2][4096];   // [buf][cb*512 + lane*8 + e]
  int tid  = threadIdx.x;
  int lane = tid & 63, wid = tid >> 6;
  int rbase = blockIdx.x*128 + wid*32;          // this wave's first row
  int fr = lane & 15, kg = lane >> 4;

  int arow0 = rbase + fr;       if(arow0 >= NN) arow0 = NN-1;
  int arow1 = rbase + 16 + fr;  if(arow1 >= NN) arow1 = NN-1;
  const f16* Ar0 = A16 + (size_t)arow0*512 + kg*8;
  const f16* Ar1 = A16 + (size_t)arow1*512 + kg*8;
  const f16* Xr0 = x16 + (size_t)arow0*128 + kg*8;
  const f16* Xr1 = x16 + (size_t)arow1*128 + kg*8;

  f32x4 acc[2][8];
  #pragma unroll
  for(int r=0;r<2;r++)
    #pragma unroll
    for(int c=0;c<8;c++) acc[r][c] = (f32x4){0.f,0.f,0.f,0.f};

  f16x8 a0, a1;
  a0 = *(const f16x8*)(Ar0); a1 = *(const f16x8*)(Ar1);
  stageB(Wf, &Blds[0][0], 0, wid, lane);

  for(int kb=0; kb<NKB; kb++){
    __syncthreads();                                   // stage(kb) done, prev reads done
    if(kb+1 < NKB) stageB(Wf, &Blds[(kb+1)&1][0], kb+1, wid, lane);
    f16x8 na0 = a0, na1 = a1;
    if(kb+1 < NKB){
      if(kb+1 < 16){ na0 = *(const f16x8*)(Ar0 + (kb+1)*32); na1 = *(const f16x8*)(Ar1 + (kb+1)*32); }
      else         { na0 = *(const f16x8*)(Xr0 + (kb+1-16)*32); na1 = *(const f16x8*)(Xr1 + (kb+1-16)*32); }
    }
    const f16* bb = &Blds[kb&1][lane*8];
    #pragma unroll
    for(int cb=0;cb<8;cb++){
      f16x8 b = *(const f16x8*)(bb + cb*512);
      acc[0][cb] = __builtin_amdgcn_mfma_f32_16x16x32_f16(a0, b, acc[0][cb], 0, 0, 0);
      acc[1][cb] = __builtin_amdgcn_mfma_f32_16x16x32_f16(a1, b, acc[1][cb], 0, 0, 0);
    }
    a0 = na0; a1 = na1;
  }

  // epilogue: bias -> relu -> +residual -> LayerNorm  (C/D: col=lane&15, row=(lane>>4)*4+q)
  float bs[8];
  #pragma unroll
  for(int cb=0;cb<8;cb++) bs[cb] = bias[cb*16 + fr];
  int g4 = kg*4;
  #pragma unroll
  for(int rh=0; rh<2; rh++){
    float vv[8][4];
    #pragma unroll
    for(int cb=0;cb<8;cb++){
      int col = cb*16 + fr;
      #pragma unroll
      for(int q=0;q<4;q++){
        float v = acc[rh][cb][q] + bs[cb];
        v = v > 0.f ? v : 0.f;
        int row = rbase + rh*16 + g4 + q;
        float res = (row < NN) ? (float)x16[(size_t)row*128 + col] : 0.f;
        vv[cb][q] = v + res;
      }
    }
    #pragma unroll
    for(int q=0;q<4;q++){
      float s1=0.f, s2=0.f;
      #pragma unroll
      for(int cb=0;cb<8;cb++){ float v=vv[cb][q]; s1+=v; s2+=v*v; }
      #pragma unroll
      for(int m=1;m<16;m<<=1){ s1 += __shfl_xor(s1,m,16); s2 += __shfl_xor(s2,m,16); }
      float mu  = s1*(1.f/128.f);
      float var = s2*(1.f/128.f) - mu*mu;
      float rs  = rsqrtf(var + 1e-5f);
      int row = rbase + rh*16 + g4 + q;
      if(row < NN){
        #pragma unroll
        for(int cb=0;cb<8;cb++){
          int col = cb*16 + fr;
          float y = (vv[cb][q]-mu)*rs*gmm[col] + bet[col];
          if(LAST) outf[(size_t)row*128 + col] = y;
          else     xnext[(size_t)row*128 + col] = (f16)y;
        }
      }
    }
  }
}

// ---------------- launch ----------------
extern "C" void kernel_launch(void* const* d_in, const int* in_sizes, int n_in,
                              void* d_out, int out_size, void* d_ws, size_t ws_size,
                              hipStream_t stream){
  const float* x    = (const float*)d_in[0];
  const int*   ei   = (const int*)d_in[1];
  const int*   et   = (const int*)d_in[2];
  const float* W    = (const float*)d_in[3];
  const float* root = (const float*)d_in[4];
  const float* bias = (const float*)d_in[5];
  const float* gmm  = (const float*)d_in[6];
  const float* bet  = (const float*)d_in[7];

  char* ws = (char*)d_ws;
  int*   cnt  = (int*)(ws + 0);            // 800000 B (reused as scatter cursor)
  int*   rowp = (int*)(ws + 800768);       // 800004 B
  int*   ssrc = (int*)(ws + 2402304);      // 3.2 MB
  int*   bsum = (int*)(ws + 5602304);      // 1 KB
  int*   boff = (int*)(ws + 5603328);      // 1 KB
  f16*   Wf   = (f16*)(ws + 5604352);      // 491520 B
  f16*   x16a = (f16*)(ws + 6095872);      // 12.8 MB
  f16*   x16b = (f16*)(ws + 18895872);     // 12.8 MB
  f16*   A16  = (f16*)(ws + 31695872);     // 51.2 MB   (total ~82.9 MB)

  hipMemsetAsync(cnt, 0, NRSEG*4, stream);
  k_hist   <<<(EE+255)/256, 256, 0, stream>>>(ei, et, cnt);
  k_reduce <<<NB_SCAN, 256, 0, stream>>>(cnt, bsum);
  k_top    <<<1, 256, 0, stream>>>(bsum, boff, rowp, NB_SCAN);
  k_scan   <<<NB_SCAN, 256, 0, stream>>>(cnt, boff, rowp);
  hipMemcpyAsync(cnt, rowp, NRSEG*4, hipMemcpyDeviceToDevice, stream);
  k_scatter<<<(EE+255)/256, 256, 0, stream>>>(ei, et, cnt, ssrc);
  k_wconv  <<<(LL*NKB*8*64+255)/256, 256, 0, stream>>>(W, root, Wf);
  k_xconv  <<<(NN*DD)/256, 256, 0, stream>>>(x, x16a);

  f16* xc = x16a; f16* xn = x16b;
  for(int l=0; l<LL; l++){
    k_agg<<<NRSEG/16, 256, 0, stream>>>(xc, rowp, ssrc, A16);
    if(l < LL-1)
      k_gemm<0><<<(NN+127)/128, 256, 0, stream>>>(A16, xc, Wf + (size_t)l*81920,
                                                  bias+l*DD, gmm+l*DD, bet+l*DD, xn, nullptr);
    else
      k_gemm<1><<<(NN+127)/128, 256, 0, stream>>>(A16, xc, Wf + (size_t)l*81920,
                                                  bias+l*DD, gmm+l*DD, bet+l*DD, nullptr, (float*)d_out);
    f16* t = xc; xc = xn; xn = t;
  }
}

// Round 4
// 291.568 us; speedup vs baseline: 1.5390x; 1.0427x over previous
//
#include <hip/hip_runtime.h>
#include <stdint.h>

#define NN 50000
#define EE 800000
#define DD 128
#define RR 4
#define LL 3
#define NRSEG (NN*RR)                    // 200000 segments (dst*4 + etype)
#define NKB 20                           // K=640 in chunks of 32
#define NB_SCAN ((NRSEG + 1023)/1024)    // 196 scan blocks
#define NBK NB_SCAN                      // bin buckets == scan blocks (seg>>10)

typedef _Float16 f16;
typedef _Float16 f16x8 __attribute__((ext_vector_type(8)));
typedef float f32x4 __attribute__((ext_vector_type(4)));

union U32H { uint32_t u; f16 h[2]; };
union U4H  { uint4 u; f16 h[8]; };

// ---------------- CSR build ----------------
__global__ __launch_bounds__(256) void k_hist(const int* __restrict__ ei, const int* __restrict__ et,
                                              int* __restrict__ cnt){
  int e = blockIdx.x*256 + threadIdx.x;
  if(e < EE) atomicAdd(&cnt[ei[EE+e]*RR + et[e]], 1);
}

__global__ __launch_bounds__(256) void k_reduce(const int* __restrict__ cnt, int* __restrict__ bsum){
  __shared__ int s[256];
  int b = blockIdx.x, t = threadIdx.x;
  int base = b*1024 + t*4;
  int v = 0;
  #pragma unroll
  for(int j=0;j<4;j++){ int i = base+j; if(i<NRSEG) v += cnt[i]; }
  s[t]=v; __syncthreads();
  for(int o=128;o>0;o>>=1){ if(t<o) s[t]+=s[t+o]; __syncthreads(); }
  if(t==0) bsum[b]=s[0];
}

__global__ __launch_bounds__(256) void k_top(const int* __restrict__ bsum, int* __restrict__ boff,
                                             int* __restrict__ rowp, int nb){
  __shared__ int s[256];
  int t=threadIdx.x;
  int v = (t<nb)? bsum[t] : 0;
  s[t]=v; __syncthreads();
  for(int o=1;o<256;o<<=1){ int x=(t>=o)?s[t-o]:0; __syncthreads(); s[t]+=x; __syncthreads(); }
  if(t<nb) boff[t] = s[t]-v;
  if(t==255) rowp[NRSEG] = s[255];
}

__global__ __launch_bounds__(256) void k_scan(const int* __restrict__ cnt, const int* __restrict__ boff,
                                              int* __restrict__ rowp){
  __shared__ int s[256];
  int b=blockIdx.x, t=threadIdx.x;
  int base = b*1024 + t*4;
  int c[4]; int tot=0;
  #pragma unroll
  for(int j=0;j<4;j++){ int i=base+j; c[j] = (i<NRSEG)? cnt[i]:0; tot+=c[j]; }
  s[t]=tot; __syncthreads();
  for(int o=1;o<256;o<<=1){ int x=(t>=o)?s[t-o]:0; __syncthreads(); s[t]+=x; __syncthreads(); }
  int run = boff[b] + s[t]-tot;
  #pragma unroll
  for(int j=0;j<4;j++){
    int i=base+j;
    if(i<NRSEG){ rowp[i]=run; run+=c[j]; }
  }
}

// Pass A: bin edges by bucket = seg>>10 into tmp (bucket-contiguous, runs coalesced).
// boff[] (== rowp[b*1024], rebuilt by k_top every call) is used as the bucket cursor.
__global__ __launch_bounds__(1024) void k_binA(const int* __restrict__ ei, const int* __restrict__ et,
                                               int* __restrict__ boff, uint2* __restrict__ tmp){
  __shared__ int bcnt[NBK];
  __shared__ int bbase[NBK];
  int t = threadIdx.x;
  if(t < NBK) bcnt[t] = 0;
  __syncthreads();

  int seg[4], src[4], bk[4], rk[4];
  #pragma unroll
  for(int j=0;j<4;j++){
    int e = blockIdx.x*4096 + j*1024 + t;
    if(e < EE){
      src[j] = ei[e];
      seg[j] = ei[EE+e]*RR + et[e];
      bk[j]  = seg[j] >> 10;
      rk[j]  = atomicAdd(&bcnt[bk[j]], 1);
    } else { seg[j] = -1; }
  }
  __syncthreads();
  if(t < NBK){
    int c = bcnt[t];
    bbase[t] = (c > 0) ? atomicAdd(&boff[t], c) : 0;
  }
  __syncthreads();
  #pragma unroll
  for(int j=0;j<4;j++){
    if(seg[j] >= 0){
      uint2 p; p.x = (uint32_t)seg[j]; p.y = (uint32_t)src[j];
      tmp[bbase[bk[j]] + rk[j]] = p;
    }
  }
}

// Pass B: one block per bucket; fine scatter within the bucket's 16KB region (single-XCD L2 locality).
__global__ __launch_bounds__(256) void k_binB(const int* __restrict__ rowp, const uint2* __restrict__ tmp,
                                              int* __restrict__ cur, int* __restrict__ ssrc){
  int b = blockIdx.x;
  int lo = rowp[b<<10];
  int hiSeg = (b+1)<<10; if(hiSeg > NRSEG) hiSeg = NRSEG;
  int hi = rowp[hiSeg];
  for(int i = lo + threadIdx.x; i < hi; i += 256){
    uint2 p = tmp[i];
    int pos = atomicAdd(&cur[p.x], 1);
    ssrc[pos] = (int)p.y;
  }
}

// ---------------- dtype converts ----------------
// Wf fragment-order: t = ((l*NKB+kb)*8+cb)*64+lane, 8 halves each:
//   Wf[t*8+e] = Wcat[k = kb*32 + (lane>>4)*8 + e][col = cb*16 + (lane&15)]
__global__ __launch_bounds__(256) void k_wconv(const float* __restrict__ W, const float* __restrict__ root,
                                               f16* __restrict__ Wf){
  int t = blockIdx.x*256 + threadIdx.x;
  if(t >= LL*NKB*8*64) return;
  int lane = t & 63;
  int cb   = (t>>6) & 7;
  int kb   = (t>>9) % NKB;
  int l    = (t>>9) / NKB;
  int col  = cb*16 + (lane&15);
  int kbase= kb*32 + (lane>>4)*8;
  f16* dst = Wf + (size_t)t*8;
  #pragma unroll
  for(int e=0;e<8;e++){
    int k = kbase+e;
    float v = (k < 4*DD) ? W[(((size_t)l*RR + (k>>7))*DD + (k&127))*DD + col]
                         : root[((size_t)l*DD + (k-4*DD))*DD + col];
    dst[e] = (f16)v;
  }
}

__global__ __launch_bounds__(256) void k_xconv(const float* __restrict__ x, f16* __restrict__ x16){
  int t = blockIdx.x*256 + threadIdx.x;
  if(t < NN*DD) x16[t] = (f16)x[t];
}

// ---------------- aggregation: one 16-lane quarter-wave per (node,relation) segment ----------------
__device__ __forceinline__ void acc8(float a[8], uint4 v){
  U4H w; w.u = v;
  #pragma unroll
  for(int k=0;k<8;k++) a[k] += (float)w.h[k];
}

__global__ __launch_bounds__(256) void k_agg(const f16* __restrict__ x16, const int* __restrict__ rowp,
                                             const int* __restrict__ ssrc, f16* __restrict__ A16){
  int seg = blockIdx.x*16 + (threadIdx.x >> 4);      // one segment per 16-lane group
  int l   = threadIdx.x & 15;
  if(seg >= NRSEG) return;

  int b = rowp[seg], e = rowp[seg+1];
  int n = e - b;
  const uint4* xl = (const uint4*)x16 + l;           // lane's 16B slice of each row

  float acc[8];
  #pragma unroll
  for(int k=0;k<8;k++) acc[k] = 0.f;

  if(n > 0){
    int c0 = ssrc[b];
    int c1 = (n > 1) ? ssrc[b+1] : c0;
    for(int j=0; j<n; j+=2){
      uint4 v0 = xl[(size_t)c0*16];
      uint4 v1 = xl[(size_t)c1*16];
      if(j+2 < n){
        c0 = ssrc[b+j+2];
        c1 = (j+3 < n) ? ssrc[b+j+3] : c0;
      }
      acc8(acc, v0);
      if(j+1 < n) acc8(acc, v1);
    }
  }

  float inv = 1.f/(float)max(n,1);
  U4H o;
  #pragma unroll
  for(int k=0;k<8;k++) o.h[k] = (f16)(acc[k]*inv);
  ((uint4*)A16)[(size_t)seg*16 + l] = o.u;
}

// ---------------- GEMM (M=NN, K=640, N=128) + fused epilogue ----------------
// Block = 256 threads (4 waves), BM=128 rows; wave owns 32 rows x 128 cols.
__device__ __forceinline__ void stageB(const f16* __restrict__ Wf, f16* lds, int kb, int wid, int lane){
  const f16* src = Wf + (size_t)kb*4096;
  #pragma unroll
  for(int j=wid;j<8;j+=4){
    __builtin_amdgcn_global_load_lds((const __attribute__((address_space(1))) void*)(src + j*512 + lane*8),
                                     (__attribute__((address_space(3))) void*)(lds + j*512), 16, 0, 0);
  }
}

template<int LAST>
__global__ __launch_bounds__(256) void k_gemm(const f16* __restrict__ A16, const f16* __restrict__ x16,
                                              const f16* __restrict__ Wf,
                                              const float* __restrict__ bias, const float* __restrict__ gmm,
                                              const float* __restrict__ bet,
                                              f16* __restrict__ xnext, float* __restrict__ outf){
  __shared__ f16 Blds[2][4096];   // [buf][cb*512 + lane*8 + e]
  int tid  = threadIdx.x;
  int lane = tid & 63, wid = tid >> 6;
  int rbase = blockIdx.x*128 + wid*32;          // this wave's first row
  int fr = lane & 15, kg = lane >> 4;

  int arow0 = rbase + fr;       if(arow0 >= NN) arow0 = NN-1;
  int arow1 = rbase + 16 + fr;  if(arow1 >= NN) arow1 = NN-1;
  const f16* Ar0 = A16 + (size_t)arow0*512 + kg*8;
  const f16* Ar1 = A16 + (size_t)arow1*512 + kg*8;
  const f16* Xr0 = x16 + (size_t)arow0*128 + kg*8;
  const f16* Xr1 = x16 + (size_t)arow1*128 + kg*8;

  f32x4 acc[2][8];
  #pragma unroll
  for(int r=0;r<2;r++)
    #pragma unroll
    for(int c=0;c<8;c++) acc[r][c] = (f32x4){0.f,0.f,0.f,0.f};

  f16x8 a0, a1;
  a0 = *(const f16x8*)(Ar0); a1 = *(const f16x8*)(Ar1);
  stageB(Wf, &Blds[0][0], 0, wid, lane);

  for(int kb=0; kb<NKB; kb++){
    __syncthreads();                                   // stage(kb) done, prev reads done
    if(kb+1 < NKB) stageB(Wf, &Blds[(kb+1)&1][0], kb+1, wid, lane);
    f16x8 na0 = a0, na1 = a1;
    if(kb+1 < NKB){
      if(kb+1 < 16){ na0 = *(const f16x8*)(Ar0 + (kb+1)*32); na1 = *(const f16x8*)(Ar1 + (kb+1)*32); }
      else         { na0 = *(const f16x8*)(Xr0 + (kb+1-16)*32); na1 = *(const f16x8*)(Xr1 + (kb+1-16)*32); }
    }
    const f16* bb = &Blds[kb&1][lane*8];
    #pragma unroll
    for(int cb=0;cb<8;cb++){
      f16x8 b = *(const f16x8*)(bb + cb*512);
      acc[0][cb] = __builtin_amdgcn_mfma_f32_16x16x32_f16(a0, b, acc[0][cb], 0, 0, 0);
      acc[1][cb] = __builtin_amdgcn_mfma_f32_16x16x32_f16(a1, b, acc[1][cb], 0, 0, 0);
    }
    a0 = na0; a1 = na1;
  }

  // epilogue: bias -> relu -> +residual -> LayerNorm  (C/D: col=lane&15, row=(lane>>4)*4+q)
  float bs[8];
  #pragma unroll
  for(int cb=0;cb<8;cb++) bs[cb] = bias[cb*16 + fr];
  int g4 = kg*4;
  #pragma unroll
  for(int rh=0; rh<2; rh++){
    float vv[8][4];
    #pragma unroll
    for(int cb=0;cb<8;cb++){
      int col = cb*16 + fr;
      #pragma unroll
      for(int q=0;q<4;q++){
        float v = acc[rh][cb][q] + bs[cb];
        v = v > 0.f ? v : 0.f;
        int row = rbase + rh*16 + g4 + q;
        float res = (row < NN) ? (float)x16[(size_t)row*128 + col] : 0.f;
        vv[cb][q] = v + res;
      }
    }
    #pragma unroll
    for(int q=0;q<4;q++){
      float s1=0.f, s2=0.f;
      #pragma unroll
      for(int cb=0;cb<8;cb++){ float v=vv[cb][q]; s1+=v; s2+=v*v; }
      #pragma unroll
      for(int m=1;m<16;m<<=1){ s1 += __shfl_xor(s1,m,16); s2 += __shfl_xor(s2,m,16); }
      float mu  = s1*(1.f/128.f);
      float var = s2*(1.f/128.f) - mu*mu;
      float rs  = rsqrtf(var + 1e-5f);
      int row = rbase + rh*16 + g4 + q;
      if(row < NN){
        #pragma unroll
        for(int cb=0;cb<8;cb++){
          int col = cb*16 + fr;
          float y = (vv[cb][q]-mu)*rs*gmm[col] + bet[col];
          if(LAST) outf[(size_t)row*128 + col] = y;
          else     xnext[(size_t)row*128 + col] = (f16)y;
        }
      }
    }
  }
}

// ---------------- launch ----------------
extern "C" void kernel_launch(void* const* d_in, const int* in_sizes, int n_in,
                              void* d_out, int out_size, void* d_ws, size_t ws_size,
                              hipStream_t stream){
  const float* x    = (const float*)d_in[0];
  const int*   ei   = (const int*)d_in[1];
  const int*   et   = (const int*)d_in[2];
  const float* W    = (const float*)d_in[3];
  const float* root = (const float*)d_in[4];
  const float* bias = (const float*)d_in[5];
  const float* gmm  = (const float*)d_in[6];
  const float* bet  = (const float*)d_in[7];

  char* ws = (char*)d_ws;
  int*   cnt  = (int*)(ws + 0);            // 800000 B (reused as binB cursor)
  int*   rowp = (int*)(ws + 800768);       // 800004 B
  int*   ssrc = (int*)(ws + 2402304);      // 3.2 MB
  int*   bsum = (int*)(ws + 5602304);      // 1 KB
  int*   boff = (int*)(ws + 5603328);      // 1 KB (also binA bucket cursor)
  f16*   Wf   = (f16*)(ws + 5604352);      // 491520 B
  f16*   x16a = (f16*)(ws + 6095872);      // 12.8 MB
  f16*   x16b = (f16*)(ws + 18895872);     // 12.8 MB
  f16*   A16  = (f16*)(ws + 31695872);     // 51.2 MB   (total ~82.9 MB)
  uint2* tmp  = (uint2*)A16;               // 6.4 MB, dead before first k_agg

  hipMemsetAsync(cnt, 0, NRSEG*4, stream);
  k_hist   <<<(EE+255)/256, 256, 0, stream>>>(ei, et, cnt);
  k_reduce <<<NB_SCAN, 256, 0, stream>>>(cnt, bsum);
  k_top    <<<1, 256, 0, stream>>>(bsum, boff, rowp, NB_SCAN);
  k_scan   <<<NB_SCAN, 256, 0, stream>>>(cnt, boff, rowp);
  hipMemcpyAsync(cnt, rowp, NRSEG*4, hipMemcpyDeviceToDevice, stream);
  k_binA   <<<NBK, 1024, 0, stream>>>(ei, et, boff, tmp);
  k_binB   <<<NBK, 256, 0, stream>>>(rowp, tmp, cnt, ssrc);
  k_wconv  <<<(LL*NKB*8*64+255)/256, 256, 0, stream>>>(W, root, Wf);
  k_xconv  <<<(NN*DD)/256, 256, 0, stream>>>(x, x16a);

  f16* xc = x16a; f16* xn = x16b;
  for(int l=0; l<LL; l++){
    k_agg<<<NRSEG/16, 256, 0, stream>>>(xc, rowp, ssrc, A16);
    if(l < LL-1)
      k_gemm<0><<<(NN+127)/128, 256, 0, stream>>>(A16, xc, Wf + (size_t)l*81920,
                                                  bias+l*DD, gmm+l*DD, bet+l*DD, xn, nullptr);
    else
      k_gemm<1><<<(NN+127)/128, 256, 0, stream>>>(A16, xc, Wf + (size_t)l*81920,
                                                  bias+l*DD, gmm+l*DD, bet+l*DD, nullptr, (float*)d_out);
    f16* t = xc; xc = xn; xn = t;
  }
}

// Round 5
// 261.203 us; speedup vs baseline: 1.7179x; 1.1162x over previous
//
#include <hip/hip_runtime.h>
#include <stdint.h>

#define NN 50000
#define EE 800000
#define DD 128
#define RR 4
#define LL 3
#define NRSEG (NN*RR)                    // 200000 segments (dst*4 + etype)
#define NKB 20                           // K=640 in chunks of 32
#define NB_SCAN ((NRSEG + 1023)/1024)    // 196 scan blocks
#define NBK NB_SCAN                      // bin buckets == scan blocks (seg>>10)
#define BKCAP 5120                       // fixed bucket region capacity (avg 4082, +16 sigma)
#define WCONV_T (LL*NKB*8*64)            // 30720 weight-conv threads

typedef _Float16 f16;
typedef _Float16 f16x8 __attribute__((ext_vector_type(8)));
typedef float f32x4 __attribute__((ext_vector_type(4)));

union U32H { uint32_t u; f16 h[2]; };
union U4H  { uint4 u; f16 h[8]; };

// ---------------- CSR build ----------------
// binA: histogram seg counts (global) + bin edges into fixed bucket regions of tmp.
__global__ __launch_bounds__(1024) void k_binA(const int* __restrict__ ei, const int* __restrict__ et,
                                               int* __restrict__ cnt, int* __restrict__ bcur,
                                               uint2* __restrict__ tmp){
  __shared__ int bcnt[NBK];
  __shared__ int bbase[NBK];
  int t = threadIdx.x;
  if(t < NBK) bcnt[t] = 0;
  __syncthreads();

  int seg[4], src[4], bk[4], rk[4];
  #pragma unroll
  for(int j=0;j<4;j++){
    int e = blockIdx.x*4096 + j*1024 + t;
    if(e < EE){
      src[j] = ei[e];
      seg[j] = ei[EE+e]*RR + et[e];
      bk[j]  = seg[j] >> 10;
      rk[j]  = atomicAdd(&bcnt[bk[j]], 1);
      atomicAdd(&cnt[seg[j]], 1);
    } else { seg[j] = -1; }
  }
  __syncthreads();
  if(t < NBK){
    int c = bcnt[t];
    bbase[t] = (c > 0) ? atomicAdd(&bcur[t], c) : 0;
  }
  __syncthreads();
  #pragma unroll
  for(int j=0;j<4;j++){
    if(seg[j] >= 0){
      uint2 p; p.x = (uint32_t)seg[j]; p.y = (uint32_t)src[j];
      tmp[(size_t)bk[j]*BKCAP + bbase[bk[j]] + rk[j]] = p;
    }
  }
}

__global__ __launch_bounds__(256) void k_reduce(const int* __restrict__ cnt, int* __restrict__ bsum){
  __shared__ int s[256];
  int b = blockIdx.x, t = threadIdx.x;
  int base = b*1024 + t*4;
  int v = 0;
  #pragma unroll
  for(int j=0;j<4;j++){ int i = base+j; if(i<NRSEG) v += cnt[i]; }
  s[t]=v; __syncthreads();
  for(int o=128;o>0;o>>=1){ if(t<o) s[t]+=s[t+o]; __syncthreads(); }
  if(t==0) bsum[b]=s[0];
}

__global__ __launch_bounds__(256) void k_top(const int* __restrict__ bsum, int* __restrict__ boff,
                                             int* __restrict__ rowp, int nb){
  __shared__ int s[256];
  int t=threadIdx.x;
  int v = (t<nb)? bsum[t] : 0;
  s[t]=v; __syncthreads();
  for(int o=1;o<256;o<<=1){ int x=(t>=o)?s[t-o]:0; __syncthreads(); s[t]+=x; __syncthreads(); }
  if(t<nb) boff[t] = s[t]-v;
  if(t==255) rowp[NRSEG] = s[255];
}

__global__ __launch_bounds__(256) void k_scan(const int* __restrict__ cnt, const int* __restrict__ boff,
                                              int* __restrict__ rowp){
  __shared__ int s[256];
  int b=blockIdx.x, t=threadIdx.x;
  int base = b*1024 + t*4;
  int c[4]; int tot=0;
  #pragma unroll
  for(int j=0;j<4;j++){ int i=base+j; c[j] = (i<NRSEG)? cnt[i]:0; tot+=c[j]; }
  s[t]=tot; __syncthreads();
  for(int o=1;o<256;o<<=1){ int x=(t>=o)?s[t-o]:0; __syncthreads(); s[t]+=x; __syncthreads(); }
  int run = boff[b] + s[t]-tot;
  #pragma unroll
  for(int j=0;j<4;j++){
    int i=base+j;
    if(i<NRSEG){ rowp[i]=run; run+=c[j]; }
  }
}

// binB: one block per bucket; positions from rowp + LDS cursors (single-XCD write locality).
__global__ __launch_bounds__(512) void k_binB(const int* __restrict__ rowp, const int* __restrict__ bcur,
                                              const uint2* __restrict__ tmp, int* __restrict__ ssrc){
  __shared__ int lcur[1024];
  int b = blockIdx.x, t = threadIdx.x;
  lcur[t] = 0; lcur[t+512] = 0;
  __syncthreads();
  int n = bcur[b];
  const uint2* src = tmp + (size_t)b*BKCAP;
  for(int i = t; i < n; i += 512){
    uint2 p = src[i];
    int pos = rowp[p.x] + atomicAdd(&lcur[p.x & 1023], 1);
    ssrc[pos] = (int)p.y;
  }
}

// ---------------- dtype converts (fused W + x) ----------------
// Wf fragment-order: t = ((l*NKB+kb)*8+cb)*64+lane, 8 halves each:
//   Wf[t*8+e] = Wcat[k = kb*32 + (lane>>4)*8 + e][col = cb*16 + (lane&15)]
__global__ __launch_bounds__(256) void k_convWX(const float* __restrict__ W, const float* __restrict__ root,
                                                f16* __restrict__ Wf,
                                                const float* __restrict__ x, f16* __restrict__ x16){
  int t = blockIdx.x*256 + threadIdx.x;
  if(t < WCONV_T){
    int lane = t & 63;
    int cb   = (t>>6) & 7;
    int kb   = (t>>9) % NKB;
    int l    = (t>>9) / NKB;
    int col  = cb*16 + (lane&15);
    int kbase= kb*32 + (lane>>4)*8;
    f16* dst = Wf + (size_t)t*8;
    #pragma unroll
    for(int e=0;e<8;e++){
      int k = kbase+e;
      float v = (k < 4*DD) ? W[(((size_t)l*RR + (k>>7))*DD + (k&127))*DD + col]
                           : root[((size_t)l*DD + (k-4*DD))*DD + col];
      dst[e] = (f16)v;
    }
  } else {
    int u = t - WCONV_T;
    if(u < NN*DD/8){
      const float4* xf = (const float4*)x + (size_t)u*2;
      float4 a = xf[0], b = xf[1];
      U4H o;
      o.h[0]=(f16)a.x; o.h[1]=(f16)a.y; o.h[2]=(f16)a.z; o.h[3]=(f16)a.w;
      o.h[4]=(f16)b.x; o.h[5]=(f16)b.y; o.h[6]=(f16)b.z; o.h[7]=(f16)b.w;
      ((uint4*)x16)[u] = o.u;
    }
  }
}

// ---------------- aggregation: one 16-lane quarter-wave per (node,relation) segment ----------------
__device__ __forceinline__ void acc8(float a[8], uint4 v){
  U4H w; w.u = v;
  #pragma unroll
  for(int k=0;k<8;k++) a[k] += (float)w.h[k];
}

__global__ __launch_bounds__(256) void k_agg(const f16* __restrict__ x16, const int* __restrict__ rowp,
                                             const int* __restrict__ ssrc, f16* __restrict__ A16){
  int seg = blockIdx.x*16 + (threadIdx.x >> 4);      // one segment per 16-lane group
  int l   = threadIdx.x & 15;
  if(seg >= NRSEG) return;

  int b = rowp[seg], e = rowp[seg+1];
  int n = e - b;
  const uint4* xl = (const uint4*)x16 + l;           // lane's 16B slice of each row

  float acc[8];
  #pragma unroll
  for(int k=0;k<8;k++) acc[k] = 0.f;

  // 4 independent gathers in flight per iteration (mean degree = 4)
  for(int base=0; base<n; base+=4){
    int m = n - base;
    int i0 = b + base;
    int c0 = ssrc[i0];
    int c1 = (m>1) ? ssrc[i0+1] : c0;
    int c2 = (m>2) ? ssrc[i0+2] : c0;
    int c3 = (m>3) ? ssrc[i0+3] : c0;
    uint4 v0 = xl[(size_t)c0*16];
    uint4 v1 = xl[(size_t)c1*16];
    uint4 v2 = xl[(size_t)c2*16];
    uint4 v3 = xl[(size_t)c3*16];
    acc8(acc, v0);
    if(m>1) acc8(acc, v1);
    if(m>2) acc8(acc, v2);
    if(m>3) acc8(acc, v3);
  }

  float inv = 1.f/(float)max(n,1);
  U4H o;
  #pragma unroll
  for(int k=0;k<8;k++) o.h[k] = (f16)(acc[k]*inv);
  ((uint4*)A16)[(size_t)seg*16 + l] = o.u;
}

// ---------------- GEMM (M=NN, K=640, N=128) + fused epilogue ----------------
// Block = 256 threads (4 waves), BM=128 rows; wave owns 32 rows x 128 cols.
__device__ __forceinline__ void stageB(const f16* __restrict__ Wf, f16* lds, int kb, int wid, int lane){
  const f16* src = Wf + (size_t)kb*4096;
  #pragma unroll
  for(int j=wid;j<8;j+=4){
    __builtin_amdgcn_global_load_lds((const __attribute__((address_space(1))) void*)(src + j*512 + lane*8),
                                     (__attribute__((address_space(3))) void*)(lds + j*512), 16, 0, 0);
  }
}

template<int LAST>
__global__ __launch_bounds__(256) void k_gemm(const f16* __restrict__ A16, const f16* __restrict__ x16,
                                              const f16* __restrict__ Wf,
                                              const float* __restrict__ bias, const float* __restrict__ gmm,
                                              const float* __restrict__ bet,
                                              f16* __restrict__ xnext, float* __restrict__ outf){
  __shared__ f16 Blds[2][4096];   // [buf][cb*512 + lane*8 + e]
  int tid  = threadIdx.x;
  int lane = tid & 63, wid = tid >> 6;
  int rbase = blockIdx.x*128 + wid*32;          // this wave's first row
  int fr = lane & 15, kg = lane >> 4;

  int arow0 = rbase + fr;       if(arow0 >= NN) arow0 = NN-1;
  int arow1 = rbase + 16 + fr;  if(arow1 >= NN) arow1 = NN-1;
  const f16* Ar0 = A16 + (size_t)arow0*512 + kg*8;
  const f16* Ar1 = A16 + (size_t)arow1*512 + kg*8;
  const f16* Xr0 = x16 + (size_t)arow0*128 + kg*8;
  const f16* Xr1 = x16 + (size_t)arow1*128 + kg*8;

  f32x4 acc[2][8];
  #pragma unroll
  for(int r=0;r<2;r++)
    #pragma unroll
    for(int c=0;c<8;c++) acc[r][c] = (f32x4){0.f,0.f,0.f,0.f};

  f16x8 a0, a1;
  a0 = *(const f16x8*)(Ar0); a1 = *(const f16x8*)(Ar1);
  stageB(Wf, &Blds[0][0], 0, wid, lane);

  for(int kb=0; kb<NKB; kb++){
    __syncthreads();                                   // stage(kb) done, prev reads done
    if(kb+1 < NKB) stageB(Wf, &Blds[(kb+1)&1][0], kb+1, wid, lane);
    f16x8 na0 = a0, na1 = a1;
    if(kb+1 < NKB){
      if(kb+1 < 16){ na0 = *(const f16x8*)(Ar0 + (kb+1)*32); na1 = *(const f16x8*)(Ar1 + (kb+1)*32); }
      else         { na0 = *(const f16x8*)(Xr0 + (kb+1-16)*32); na1 = *(const f16x8*)(Xr1 + (kb+1-16)*32); }
    }
    const f16* bb = &Blds[kb&1][lane*8];
    #pragma unroll
    for(int cb=0;cb<8;cb++){
      f16x8 b = *(const f16x8*)(bb + cb*512);
      acc[0][cb] = __builtin_amdgcn_mfma_f32_16x16x32_f16(a0, b, acc[0][cb], 0, 0, 0);
      acc[1][cb] = __builtin_amdgcn_mfma_f32_16x16x32_f16(a1, b, acc[1][cb], 0, 0, 0);
    }
    a0 = na0; a1 = na1;
  }

  // epilogue: bias -> relu -> +residual -> LayerNorm  (C/D: col=lane&15, row=(lane>>4)*4+q)
  float bs[8];
  #pragma unroll
  for(int cb=0;cb<8;cb++) bs[cb] = bias[cb*16 + fr];
  int g4 = kg*4;
  #pragma unroll
  for(int rh=0; rh<2; rh++){
    float vv[8][4];
    #pragma unroll
    for(int cb=0;cb<8;cb++){
      int col = cb*16 + fr;
      #pragma unroll
      for(int q=0;q<4;q++){
        float v = acc[rh][cb][q] + bs[cb];
        v = v > 0.f ? v : 0.f;
        int row = rbase + rh*16 + g4 + q;
        float res = (row < NN) ? (float)x16[(size_t)row*128 + col] : 0.f;
        vv[cb][q] = v + res;
      }
    }
    #pragma unroll
    for(int q=0;q<4;q++){
      float s1=0.f, s2=0.f;
      #pragma unroll
      for(int cb=0;cb<8;cb++){ float v=vv[cb][q]; s1+=v; s2+=v*v; }
      #pragma unroll
      for(int m=1;m<16;m<<=1){ s1 += __shfl_xor(s1,m,16); s2 += __shfl_xor(s2,m,16); }
      float mu  = s1*(1.f/128.f);
      float var = s2*(1.f/128.f) - mu*mu;
      float rs  = rsqrtf(var + 1e-5f);
      int row = rbase + rh*16 + g4 + q;
      if(row < NN){
        #pragma unroll
        for(int cb=0;cb<8;cb++){
          int col = cb*16 + fr;
          float y = (vv[cb][q]-mu)*rs*gmm[col] + bet[col];
          if(LAST) outf[(size_t)row*128 + col] = y;
          else     xnext[(size_t)row*128 + col] = (f16)y;
        }
      }
    }
  }
}

// ---------------- launch ----------------
extern "C" void kernel_launch(void* const* d_in, const int* in_sizes, int n_in,
                              void* d_out, int out_size, void* d_ws, size_t ws_size,
                              hipStream_t stream){
  const float* x    = (const float*)d_in[0];
  const int*   ei   = (const int*)d_in[1];
  const int*   et   = (const int*)d_in[2];
  const float* W    = (const float*)d_in[3];
  const float* root = (const float*)d_in[4];
  const float* bias = (const float*)d_in[5];
  const float* gmm  = (const float*)d_in[6];
  const float* bet  = (const float*)d_in[7];

  char* ws = (char*)d_ws;
  int*   cnt  = (int*)(ws + 0);            // 800000 B seg histogram
  int*   bcur = (int*)(ws + 800000);       // 784 B bucket cursor (memset together with cnt)
  int*   rowp = (int*)(ws + 801792);       // 800004 B
  int*   bsum = (int*)(ws + 1602048);      // 1 KB
  int*   boff = (int*)(ws + 1603072);      // 1 KB
  int*   ssrc = (int*)(ws + 1604096);      // 3.2 MB
  f16*   Wf   = (f16*)(ws + 4804608);      // 491520 B
  f16*   x16a = (f16*)(ws + 5296128);      // 12.8 MB
  f16*   x16b = (f16*)(ws + 18096128);     // 12.8 MB
  f16*   A16  = (f16*)(ws + 30896128);     // 51.2 MB  (total ~82.1 MB)
  uint2* tmp  = (uint2*)A16;               // 196*5120*8 = 8.03 MB, dead before first k_agg

  hipMemsetAsync(cnt, 0, 800784, stream);                       // cnt + bcur
  k_binA  <<<NBK, 1024, 0, stream>>>(ei, et, cnt, bcur, tmp);
  k_reduce<<<NB_SCAN, 256, 0, stream>>>(cnt, bsum);
  k_top   <<<1, 256, 0, stream>>>(bsum, boff, rowp, NB_SCAN);
  k_scan  <<<NB_SCAN, 256, 0, stream>>>(cnt, boff, rowp);
  k_binB  <<<NBK, 512, 0, stream>>>(rowp, bcur, tmp, ssrc);
  k_convWX<<<(WCONV_T + NN*DD/8 + 255)/256, 256, 0, stream>>>(W, root, Wf, x, x16a);

  f16* xc = x16a; f16* xn = x16b;
  for(int l=0; l<LL; l++){
    k_agg<<<NRSEG/16, 256, 0, stream>>>(xc, rowp, ssrc, A16);
    if(l < LL-1)
      k_gemm<0><<<(NN+127)/128, 256, 0, stream>>>(A16, xc, Wf + (size_t)l*81920,
                                                  bias+l*DD, gmm+l*DD, bet+l*DD, xn, nullptr);
    else
      k_gemm<1><<<(NN+127)/128, 256, 0, stream>>>(A16, xc, Wf + (size_t)l*81920,
                                                  bias+l*DD, gmm+l*DD, bet+l*DD, nullptr, (float*)d_out);
    f16* t = xc; xc = xn; xn = t;
  }
}